// Round 5
// baseline (109.062 us; speedup 1.0000x reference)
//
#include <hip/hip_runtime.h>
#include <math.h>

// Problem constants: B=4, C=128, H=W=96, E=4, C8=16, scale=2 (baked in)
#define Bn 4
#define Cc 128
#define Hh 96
#define Ww 96
#define H2c 192
#define W2c 192
#define HW (Hh*Ww)

// Workspace layout (floats):
//   [WC_OFF, +4*2048)  Wc_t[cls][c][o]  (transposed: c-major, 16 o contiguous)
//   [WE_OFF, +4*2048)  We  [cls][c][o]  (native wexp layout)
//   [TAP_OFF, +16)     per-class {tx, ty, Dx, Dy}
#define WC_OFF 0
#define WE_OFF (4*2048)
#define TAP_OFF (8*2048)

// ---------------------------------------------------------------------------
// K1: per-class tiny MLP -> routing/offsets; mix expert weights; tap constants.
__global__ __launch_bounds__(256) void k1_mix(
    const float* __restrict__ wcomp, const float* __restrict__ wexp,
    const float* __restrict__ bw1, const float* __restrict__ bb1,
    const float* __restrict__ bw2, const float* __restrict__ bb2,
    const float* __restrict__ rw,  const float* __restrict__ rb,
    const float* __restrict__ ow,  const float* __restrict__ ob,
    float* __restrict__ ws)
{
    __shared__ float e1[64], e2[64], rr[4], of[2];
    const int tid   = threadIdx.x;
    const int cls   = blockIdx.x >> 4;   // pcy*2 + pcx
    const int chunk = blockIdx.x & 15;
    const float chv = (cls & 2) ? 0.25f : -0.25f;  // row fractional coord
    const float cwv = (cls & 1) ? 0.25f : -0.25f;  // col fractional coord

    if (tid < 64) {
        float h = bw1[tid*3+0]*0.5f + bw1[tid*3+1]*chv + bw1[tid*3+2]*cwv + bb1[tid];
        e1[tid] = fmaxf(h, 0.f);
    }
    __syncthreads();
    if (tid < 64) {
        float s = bb2[tid];
        for (int i = 0; i < 64; ++i) s += bw2[tid*64+i]*e1[i];
        e2[tid] = fmaxf(s, 0.f);
    }
    __syncthreads();
    if (tid < 6) {
        if (tid < 4) {
            float s = rb[tid];
            for (int i = 0; i < 64; ++i) s += rw[tid*64+i]*e2[i];
            rr[tid] = 1.f/(1.f+expf(-s));
        } else {
            const int d = tid - 4;
            float s = ob[d];
            for (int i = 0; i < 64; ++i) s += ow[d*64+i]*e2[i];
            of[d] = s;
        }
    }
    __syncthreads();
    const float r0 = rr[0], r1 = rr[1], r2 = rr[2], r3 = rr[3];

    if (tid < 128) {
        // Wc: source [o][c] (idx = o*128+c), dest transposed [c][o]
        const int idx = chunk*128 + tid;
        const int o = idx >> 7, c = idx & 127;
        const float v = r0*wcomp[idx] + r1*wcomp[2048+idx]
                      + r2*wcomp[4096+idx] + r3*wcomp[6144+idx];
        ws[WC_OFF + cls*2048 + c*16 + o] = v;
    } else {
        // We: native [c][o] layout, straight copy of the mix
        const int idx = chunk*128 + (tid - 128);
        ws[WE_OFF + cls*2048 + idx] =
            r0*wexp[idx] + r1*wexp[2048+idx] + r2*wexp[4096+idx] + r3*wexp[6144+idx];
    }
    if (chunk == 0 && tid == 0) {
        const float fx = cwv + of[0];
        const float fy = chv + of[1];
        const float Dx = floorf(fx), Dy = floorf(fy);
        ws[TAP_OFF + cls*4 + 0] = fx - Dx;
        ws[TAP_OFF + cls*4 + 1] = fy - Dy;
        ws[TAP_OFF + cls*4 + 2] = Dx;
        ws[TAP_OFF + cls*4 + 3] = Dy;
    }
}

// Edge remap: taps at c0, c0+1 clamped to 2-wide window [base, base+1], with
// zero-padding folded into the two weights. (Verified rounds 1-4.)
__device__ __forceinline__ void remap_axis(int c0, int last, float w0, float w1,
                                           int& base, float& a0, float& a1)
{
    base = min(max(c0, 0), last - 1);
    if (c0 >= 0 && c0 < last) { a0 = w0;  a1 = w1;  }
    else if (c0 == -1)        { a0 = w1;  a1 = 0.f; }
    else if (c0 == last)      { a0 = 0.f; a1 = w0;  }
    else                      { a0 = 0.f; a1 = 0.f; }
}

// ---------------------------------------------------------------------------
// Fused compress+expand, class-pure blocks, SGPR weights.
// 2304 blocks x 256 threads (4 waves). Block = 64 consecutive pixels of the
// 96x96 half-res grid of ONE class; wave g owns channels [g*32, g*32+32).
// Weight addresses are blockIdx-uniform -> compiler emits s_load; FMAs read
// SGPR operands. LDS used only for the 16-wide cross-wave comp reduce.
__global__ __launch_bounds__(256, 4) void k2_fused(
    const float* __restrict__ x, const float* __restrict__ wsr,
    float* __restrict__ out)
{
    __shared__ float lPart[4*16*64];               // [g][o][xl] 16 KB

    const int tid = threadIdx.x;
    const int xl  = tid & 63;
    const int grp = tid >> 6;

    // XCD-paired swizzle: 2304 = 8 XCDs * 288 slots; the 4 classes of a tile
    // land consecutively on ONE XCD (stride-2 stores merge, x rows shared).
    const int n = blockIdx.x;
    const int w = (n & 7) * 288 + (n >> 3);
    const int px = w & 1, py = (w >> 1) & 1;
    const int w2 = w >> 2;            // 0..575
    const int tile = w2 % 144;        // spatial tile
    const int b    = w2 / 144;
    const int cls  = (py << 1) | px;

    const float* Wc = wsr + WC_OFF + cls*2048;   // uniform -> s_load
    const float* We = wsr + WE_OFF + cls*2048;   // uniform -> s_load

    // pixel decode: flat index in 96x96 half-res grid
    const int idx = tile*64 + xl;
    const int j = idx / 96;           // half-res row
    const int i = idx - j*96;         // half-res col

    const float tx = wsr[TAP_OFF + cls*4 + 0];
    const float ty = wsr[TAP_OFF + cls*4 + 1];
    const int   Dx = (int)wsr[TAP_OFF + cls*4 + 2];
    const int   Dy = (int)wsr[TAP_OFF + cls*4 + 3];
    int cb, rbw; float ax0, ax1, ay0, ay1;
    remap_axis(i + Dx, Ww - 1, 1.f - tx, tx, cb,  ax0, ax1);
    remap_axis(j + Dy, Hh - 1, 1.f - ty, ty, rbw, ay0, ay1);
    const float w00 = ay0*ax0, w01 = ay0*ax1, w10 = ay1*ax0, w11 = ay1*ax1;
    const float* xb = x + (size_t)b*Cc*HW + rbw*Ww + cb;

    // ---- P1: partial compress over this wave's 32 channels; fea -> VGPRs ----
    float comp[16];
    #pragma unroll
    for (int o = 0; o < 16; ++o) comp[o] = 0.f;
    float fea[32];

    #pragma unroll
    for (int kk = 0; kk < 32; ++kk) {
        const int c = grp*32 + kk;
        const float* p = xb + (size_t)c*HW;
        const float f = w00*p[0] + w01*p[1] + w10*p[Ww] + w11*p[Ww+1];
        fea[kk] = f;
        const float4 q0 = *reinterpret_cast<const float4*>(Wc + c*16 +  0);
        const float4 q1 = *reinterpret_cast<const float4*>(Wc + c*16 +  4);
        const float4 q2 = *reinterpret_cast<const float4*>(Wc + c*16 +  8);
        const float4 q3 = *reinterpret_cast<const float4*>(Wc + c*16 + 12);
        comp[ 0] += q0.x*f; comp[ 1] += q0.y*f; comp[ 2] += q0.z*f; comp[ 3] += q0.w*f;
        comp[ 4] += q1.x*f; comp[ 5] += q1.y*f; comp[ 6] += q1.z*f; comp[ 7] += q1.w*f;
        comp[ 8] += q2.x*f; comp[ 9] += q2.y*f; comp[10] += q2.z*f; comp[11] += q2.w*f;
        comp[12] += q3.x*f; comp[13] += q3.y*f; comp[14] += q3.z*f; comp[15] += q3.w*f;
    }
    #pragma unroll
    for (int o = 0; o < 16; ++o) lPart[(grp*16 + o)*64 + xl] = comp[o];
    __syncthreads();

    // ---- cross-wave reduce; result lands in lPart's g=0 region (aliasing safe:
    // each (o,xl) g=0 slot is read as the g=0 term and rewritten by the SAME thread)
    #pragma unroll
    for (int jj = 0; jj < 4; ++jj) {
        const int o = grp*4 + jj;
        const float s = lPart[(o     )*64 + xl] + lPart[(16 + o)*64 + xl]
                      + lPart[(32 + o)*64 + xl] + lPart[(48 + o)*64 + xl];
        lPart[o*64 + xl] = s;
    }
    __syncthreads();

    // ---- P2: expand + residual (fea from regs), We via SGPR loads ----
    float cf[16];
    #pragma unroll
    for (int o = 0; o < 16; ++o) cf[o] = lPart[o*64 + xl];

    const int xg = 2*i + px;
    const int yg = 2*j + py;
    float* op = out + ((size_t)(b*Cc)*H2c + yg)*W2c + xg;

    #pragma unroll
    for (int kk = 0; kk < 32; ++kk) {
        const int c = grp*32 + kk;
        const float4 q0 = *reinterpret_cast<const float4*>(We + c*16 +  0);
        const float4 q1 = *reinterpret_cast<const float4*>(We + c*16 +  4);
        const float4 q2 = *reinterpret_cast<const float4*>(We + c*16 +  8);
        const float4 q3 = *reinterpret_cast<const float4*>(We + c*16 + 12);
        float acc = fea[kk]
            + q0.x*cf[ 0] + q0.y*cf[ 1] + q0.z*cf[ 2] + q0.w*cf[ 3]
            + q1.x*cf[ 4] + q1.y*cf[ 5] + q1.z*cf[ 6] + q1.w*cf[ 7]
            + q2.x*cf[ 8] + q2.y*cf[ 9] + q2.z*cf[10] + q2.w*cf[11]
            + q3.x*cf[12] + q3.y*cf[13] + q3.z*cf[14] + q3.w*cf[15];
        op[(size_t)c*(H2c*W2c)] = acc;
    }
}

extern "C" void kernel_launch(void* const* d_in, const int* in_sizes, int n_in,
                              void* d_out, int out_size, void* d_ws, size_t ws_size,
                              hipStream_t stream) {
    const float* x     = (const float*)d_in[0];
    const float* wcomp = (const float*)d_in[1];
    const float* wexp  = (const float*)d_in[2];
    const float* bw1   = (const float*)d_in[3];
    const float* bb1   = (const float*)d_in[4];
    const float* bw2   = (const float*)d_in[5];
    const float* bb2   = (const float*)d_in[6];
    const float* rw    = (const float*)d_in[7];
    const float* rb    = (const float*)d_in[8];
    const float* ow    = (const float*)d_in[9];
    const float* ob    = (const float*)d_in[10];
    float* out = (float*)d_out;
    float* ws  = (float*)d_ws;   // ~66 KB

    k1_mix<<<64, 256, 0, stream>>>(wcomp, wexp, bw1, bb1, bw2, bb2, rw, rb, ow, ob, ws);
    k2_fused<<<2304, 256, 0, stream>>>(x, ws, out);
}

// Round 6
// 63.236 us; speedup vs baseline: 1.7247x; 1.7247x over previous
//
#include <hip/hip_runtime.h>
#include <math.h>

// Problem constants: B=4, C=128, H=W=96, E=4, C8=16, scale=2 (baked in)
#define Bn 4
#define Cc 128
#define Hh 96
#define Ww 96
#define H2c 192
#define W2c 192
#define HW (Hh*Ww)

// Workspace layout (floats):
//   [WC_OFF, +4*2048)  Wc_t[cls][c][o]  (transposed: c-major, 16 o contiguous)
//   [WE_OFF, +4*2048)  We  [cls][c][o]  (native wexp layout)
//   [TAP_OFF, +16)     per-class {tx, ty, Dx, Dy}
#define WC_OFF 0
#define WE_OFF (4*2048)
#define TAP_OFF (8*2048)

// ---------------------------------------------------------------------------
// K1: per-class tiny MLP -> routing/offsets; mix expert weights; tap constants.
__global__ __launch_bounds__(256) void k1_mix(
    const float* __restrict__ wcomp, const float* __restrict__ wexp,
    const float* __restrict__ bw1, const float* __restrict__ bb1,
    const float* __restrict__ bw2, const float* __restrict__ bb2,
    const float* __restrict__ rw,  const float* __restrict__ rb,
    const float* __restrict__ ow,  const float* __restrict__ ob,
    float* __restrict__ ws)
{
    __shared__ float e1[64], e2[64], rr[4], of[2];
    const int tid   = threadIdx.x;
    const int cls   = blockIdx.x >> 4;   // pcy*2 + pcx
    const int chunk = blockIdx.x & 15;
    const float chv = (cls & 2) ? 0.25f : -0.25f;  // row fractional coord
    const float cwv = (cls & 1) ? 0.25f : -0.25f;  // col fractional coord

    if (tid < 64) {
        float h = bw1[tid*3+0]*0.5f + bw1[tid*3+1]*chv + bw1[tid*3+2]*cwv + bb1[tid];
        e1[tid] = fmaxf(h, 0.f);
    }
    __syncthreads();
    if (tid < 64) {
        float s = bb2[tid];
        for (int i = 0; i < 64; ++i) s += bw2[tid*64+i]*e1[i];
        e2[tid] = fmaxf(s, 0.f);
    }
    __syncthreads();
    if (tid < 6) {
        if (tid < 4) {
            float s = rb[tid];
            for (int i = 0; i < 64; ++i) s += rw[tid*64+i]*e2[i];
            rr[tid] = 1.f/(1.f+expf(-s));
        } else {
            const int d = tid - 4;
            float s = ob[d];
            for (int i = 0; i < 64; ++i) s += ow[d*64+i]*e2[i];
            of[d] = s;
        }
    }
    __syncthreads();
    const float r0 = rr[0], r1 = rr[1], r2 = rr[2], r3 = rr[3];

    if (tid < 128) {
        // Wc: source [o][c] (idx = o*128+c), dest transposed [c][o]
        const int idx = chunk*128 + tid;
        const int o = idx >> 7, c = idx & 127;
        const float v = r0*wcomp[idx] + r1*wcomp[2048+idx]
                      + r2*wcomp[4096+idx] + r3*wcomp[6144+idx];
        ws[WC_OFF + cls*2048 + c*16 + o] = v;
    } else {
        // We: native [c][o] layout, straight copy of the mix
        const int idx = chunk*128 + (tid - 128);
        ws[WE_OFF + cls*2048 + idx] =
            r0*wexp[idx] + r1*wexp[2048+idx] + r2*wexp[4096+idx] + r3*wexp[6144+idx];
    }
    if (chunk == 0 && tid == 0) {
        const float fx = cwv + of[0];
        const float fy = chv + of[1];
        const float Dx = floorf(fx), Dy = floorf(fy);
        ws[TAP_OFF + cls*4 + 0] = fx - Dx;
        ws[TAP_OFF + cls*4 + 1] = fy - Dy;
        ws[TAP_OFF + cls*4 + 2] = Dx;
        ws[TAP_OFF + cls*4 + 3] = Dy;
    }
}

// Edge remap: taps at c0, c0+1 clamped to 2-wide window [base, base+1], with
// zero-padding folded into the two weights. (Verified rounds 1-5.)
__device__ __forceinline__ void remap_axis(int c0, int last, float w0, float w1,
                                           int& base, float& a0, float& a1)
{
    base = min(max(c0, 0), last - 1);
    if (c0 >= 0 && c0 < last) { a0 = w0;  a1 = w1;  }
    else if (c0 == -1)        { a0 = w1;  a1 = 0.f; }
    else if (c0 == last)      { a0 = 0.f; a1 = w0;  }
    else                      { a0 = 0.f; a1 = 0.f; }
}

// ---------------------------------------------------------------------------
// Fused compress+expand, class-pure blocks, 2 pixels/thread.
// 1152 blocks x 256 threads (4 waves). Block = 128 consecutive pixels (64
// lanes x 2 adjacent half-res cols) of ONE class; wave g owns channels
// [g*32, g*32+32). Weights staged in LDS (wave-uniform broadcast reads, 0
// conflicts); weight reads amortize over 2 pixels; taps load as shared
// 4-col windows (2x float2 per row per channel, 8B aligned).
__global__ __launch_bounds__(256, 3) void k2_fused(
    const float* __restrict__ x, const float* __restrict__ wsr,
    float* __restrict__ out)
{
    __shared__ __align__(16) float lWc[2048];        //  8 KB [c][o]
    __shared__ __align__(16) float lWe[2048];        //  8 KB [c][o]
    __shared__ __align__(16) float lPart[4*16*128];  // 32 KB [g][o][slot]

    const int tid = threadIdx.x;
    const int xl  = tid & 63;
    const int grp = tid >> 6;

    // XCD-paired swizzle: 1152 = 8 XCDs * 144 slots; the 4 classes of a tile
    // are consecutive on ONE XCD (stride-2 stores merge, x rows shared in L2).
    const int n = blockIdx.x;
    const int w = (n & 7) * 144 + (n >> 3);
    const int cls  = w & 3;
    const int px   = cls & 1, py = (cls >> 1) & 1;
    const int rest = w >> 2;         // 0..287
    const int tile = rest % 72;
    const int b    = rest / 72;

    // stage this class's weights (coalesced float4, 2 per thread each)
    {
        const float4* sc = reinterpret_cast<const float4*>(wsr + WC_OFF + cls*2048);
        const float4* se = reinterpret_cast<const float4*>(wsr + WE_OFF + cls*2048);
        reinterpret_cast<float4*>(lWc)[tid]     = sc[tid];
        reinterpret_cast<float4*>(lWc)[tid+256] = sc[tid+256];
        reinterpret_cast<float4*>(lWe)[tid]     = se[tid];
        reinterpret_cast<float4*>(lWe)[tid+256] = se[tid+256];
    }

    // pixel decode: thread owns half-res pixels (j, i0) and (j, i0+1)
    const int pix0 = (tile*64 + xl)*2;
    const int j  = pix0 / 96;
    const int i0 = pix0 - j*96;

    const float tx = wsr[TAP_OFF + cls*4 + 0];
    const float ty = wsr[TAP_OFF + cls*4 + 1];
    const int   Dx = (int)wsr[TAP_OFF + cls*4 + 2];
    const int   Dy = (int)wsr[TAP_OFF + cls*4 + 3];

    int rbw; float ay0, ay1;
    remap_axis(j + Dy, Hh - 1, 1.f - ty, ty, rbw, ay0, ay1);

    // shared 4-col window [base, base+3], even base (8B-aligned float2 loads)
    int base = i0 + Dx;
    base = max(0, min(Ww - 4, base));
    base &= ~1;

    // per-pixel window coefficients (tap weights + zero-pad folded; y folded)
    float bt[2][4], bb_[2][4];
    #pragma unroll
    for (int p = 0; p < 2; ++p) {
        int bp; float a0, a1;
        remap_axis(i0 + p + Dx, Ww - 1, 1.f - tx, tx, bp, a0, a1);
        const int k = bp - base;     // 0..2 guaranteed
        const float c0 = (k == 0) ? a0 : 0.f;
        const float c1 = (k == 0) ? a1 : ((k == 1) ? a0 : 0.f);
        const float c2 = (k == 1) ? a1 : ((k == 2) ? a0 : 0.f);
        const float c3 = (k == 2) ? a1 : 0.f;
        bt[p][0]  = ay0*c0; bt[p][1]  = ay0*c1; bt[p][2]  = ay0*c2; bt[p][3]  = ay0*c3;
        bb_[p][0] = ay1*c0; bb_[p][1] = ay1*c1; bb_[p][2] = ay1*c2; bb_[p][3] = ay1*c3;
    }

    const float* xb = x + (size_t)b*Cc*HW + rbw*Ww + base;
    __syncthreads();

    // ---- P1: partial compress over this wave's 32 channels, 2 px each ----
    float fea[2][32];
    float comp[2][16];
    #pragma unroll
    for (int o = 0; o < 16; ++o) { comp[0][o] = 0.f; comp[1][o] = 0.f; }

    #pragma unroll
    for (int kk = 0; kk < 32; ++kk) {
        const int c = grp*32 + kk;
        const float* p = xb + (size_t)c*HW;
        const float2 t0 = *reinterpret_cast<const float2*>(p);
        const float2 t1 = *reinterpret_cast<const float2*>(p + 2);
        const float2 u0 = *reinterpret_cast<const float2*>(p + Ww);
        const float2 u1 = *reinterpret_cast<const float2*>(p + Ww + 2);
        const float f0 = bt[0][0]*t0.x + bt[0][1]*t0.y + bt[0][2]*t1.x + bt[0][3]*t1.y
                       + bb_[0][0]*u0.x + bb_[0][1]*u0.y + bb_[0][2]*u1.x + bb_[0][3]*u1.y;
        const float f1 = bt[1][0]*t0.x + bt[1][1]*t0.y + bt[1][2]*t1.x + bt[1][3]*t1.y
                       + bb_[1][0]*u0.x + bb_[1][1]*u0.y + bb_[1][2]*u1.x + bb_[1][3]*u1.y;
        fea[0][kk] = f0;
        fea[1][kk] = f1;
        const float4 q0 = *reinterpret_cast<const float4*>(lWc + c*16 +  0);
        const float4 q1 = *reinterpret_cast<const float4*>(lWc + c*16 +  4);
        const float4 q2 = *reinterpret_cast<const float4*>(lWc + c*16 +  8);
        const float4 q3 = *reinterpret_cast<const float4*>(lWc + c*16 + 12);
        comp[0][ 0] += q0.x*f0; comp[0][ 1] += q0.y*f0; comp[0][ 2] += q0.z*f0; comp[0][ 3] += q0.w*f0;
        comp[0][ 4] += q1.x*f0; comp[0][ 5] += q1.y*f0; comp[0][ 6] += q1.z*f0; comp[0][ 7] += q1.w*f0;
        comp[0][ 8] += q2.x*f0; comp[0][ 9] += q2.y*f0; comp[0][10] += q2.z*f0; comp[0][11] += q2.w*f0;
        comp[0][12] += q3.x*f0; comp[0][13] += q3.y*f0; comp[0][14] += q3.z*f0; comp[0][15] += q3.w*f0;
        comp[1][ 0] += q0.x*f1; comp[1][ 1] += q0.y*f1; comp[1][ 2] += q0.z*f1; comp[1][ 3] += q0.w*f1;
        comp[1][ 4] += q1.x*f1; comp[1][ 5] += q1.y*f1; comp[1][ 6] += q1.z*f1; comp[1][ 7] += q1.w*f1;
        comp[1][ 8] += q2.x*f1; comp[1][ 9] += q2.y*f1; comp[1][10] += q2.z*f1; comp[1][11] += q2.w*f1;
        comp[1][12] += q3.x*f1; comp[1][13] += q3.y*f1; comp[1][14] += q3.z*f1; comp[1][15] += q3.w*f1;
    }
    #pragma unroll
    for (int o = 0; o < 16; ++o) {
        const float2 v = {comp[0][o], comp[1][o]};
        *reinterpret_cast<float2*>(&lPart[(grp*16 + o)*128 + 2*xl]) = v;
    }
    __syncthreads();

    // ---- cross-wave reduce into g=0 region (same-thread RMW per slot) ----
    #pragma unroll
    for (int jj = 0; jj < 4; ++jj) {
        const int o = grp*4 + jj;
        float sx = 0.f, sy = 0.f;
        #pragma unroll
        for (int g = 0; g < 4; ++g) {
            const float2 v = *reinterpret_cast<const float2*>(&lPart[(g*16 + o)*128 + 2*xl]);
            sx += v.x; sy += v.y;
        }
        const float2 s = {sx, sy};
        *reinterpret_cast<float2*>(&lPart[o*128 + 2*xl]) = s;
    }
    __syncthreads();

    // ---- P2: expand + residual (fea from regs) ----
    float cf[2][16];
    #pragma unroll
    for (int o = 0; o < 16; ++o) {
        const float2 v = *reinterpret_cast<const float2*>(&lPart[o*128 + 2*xl]);
        cf[0][o] = v.x; cf[1][o] = v.y;
    }

    const int yg = 2*j + py;
    const int xg = 2*i0 + px;
    float* op = out + ((size_t)(b*Cc)*H2c + yg)*W2c + xg;

    #pragma unroll
    for (int kk = 0; kk < 32; ++kk) {
        const int c = grp*32 + kk;
        const float4 q0 = *reinterpret_cast<const float4*>(lWe + c*16 +  0);
        const float4 q1 = *reinterpret_cast<const float4*>(lWe + c*16 +  4);
        const float4 q2 = *reinterpret_cast<const float4*>(lWe + c*16 +  8);
        const float4 q3 = *reinterpret_cast<const float4*>(lWe + c*16 + 12);
        const float a0 = fea[0][kk]
            + q0.x*cf[0][ 0] + q0.y*cf[0][ 1] + q0.z*cf[0][ 2] + q0.w*cf[0][ 3]
            + q1.x*cf[0][ 4] + q1.y*cf[0][ 5] + q1.z*cf[0][ 6] + q1.w*cf[0][ 7]
            + q2.x*cf[0][ 8] + q2.y*cf[0][ 9] + q2.z*cf[0][10] + q2.w*cf[0][11]
            + q3.x*cf[0][12] + q3.y*cf[0][13] + q3.z*cf[0][14] + q3.w*cf[0][15];
        const float a1 = fea[1][kk]
            + q0.x*cf[1][ 0] + q0.y*cf[1][ 1] + q0.z*cf[1][ 2] + q0.w*cf[1][ 3]
            + q1.x*cf[1][ 4] + q1.y*cf[1][ 5] + q1.z*cf[1][ 6] + q1.w*cf[1][ 7]
            + q2.x*cf[1][ 8] + q2.y*cf[1][ 9] + q2.z*cf[1][10] + q2.w*cf[1][11]
            + q3.x*cf[1][12] + q3.y*cf[1][13] + q3.z*cf[1][14] + q3.w*cf[1][15];
        float* dst = op + (size_t)c*(H2c*W2c);
        dst[0] = a0;
        dst[2] = a1;
    }
}

extern "C" void kernel_launch(void* const* d_in, const int* in_sizes, int n_in,
                              void* d_out, int out_size, void* d_ws, size_t ws_size,
                              hipStream_t stream) {
    const float* x     = (const float*)d_in[0];
    const float* wcomp = (const float*)d_in[1];
    const float* wexp  = (const float*)d_in[2];
    const float* bw1   = (const float*)d_in[3];
    const float* bb1   = (const float*)d_in[4];
    const float* bw2   = (const float*)d_in[5];
    const float* bb2   = (const float*)d_in[6];
    const float* rw    = (const float*)d_in[7];
    const float* rb    = (const float*)d_in[8];
    const float* ow    = (const float*)d_in[9];
    const float* ob    = (const float*)d_in[10];
    float* out = (float*)d_out;
    float* ws  = (float*)d_ws;   // ~66 KB

    k1_mix<<<64, 256, 0, stream>>>(wcomp, wexp, bw1, bb1, bw2, bb2, rw, rb, ow, ob, ws);
    k2_fused<<<1152, 256, 0, stream>>>(x, ws, out);
}

// Round 7
// 49.233 us; speedup vs baseline: 2.2152x; 1.2844x over previous
//
#include <hip/hip_runtime.h>
#include <math.h>

// Problem constants: B=4, C=128, H=W=96, E=4, C8=16, scale=2 (baked in)
#define Bn 4
#define Cc 128
#define Hh 96
#define Ww 96
#define H2c 192
#define W2c 192
#define HW (Hh*Ww)

// Workspace layout:
//   floats: [WC_OFF,+4*2048) Wc_t[cls][c][o] ; [WE_OFF,+4*2048) We[cls][c][o]
//           [TAP_OFF,+16) per-class {tx,ty,Dx,Dy}
//   ushort (bf16) at float-offset M_OFF: M[cls][c_out][128]  (folded We*Wc+I)
#define WC_OFF 0
#define WE_OFF (4*2048)
#define TAP_OFF (8*2048)
#define M_OFF  16640          // float offset; byte 66560 (16B aligned)

typedef float  f32x4  __attribute__((ext_vector_type(4)));
typedef short  s16x8  __attribute__((ext_vector_type(8)));

__device__ __forceinline__ unsigned f2bf(float f) {
    unsigned u = __float_as_uint(f);
    return (u + 0x7FFFu + ((u >> 16) & 1u)) >> 16;   // RNE to bf16
}

// ---------------------------------------------------------------------------
// K1: per-class tiny MLP -> routing/offsets; mix expert weights; tap constants.
__global__ __launch_bounds__(256) void k1_mix(
    const float* __restrict__ wcomp, const float* __restrict__ wexp,
    const float* __restrict__ bw1, const float* __restrict__ bb1,
    const float* __restrict__ bw2, const float* __restrict__ bb2,
    const float* __restrict__ rw,  const float* __restrict__ rb,
    const float* __restrict__ ow,  const float* __restrict__ ob,
    float* __restrict__ ws)
{
    __shared__ float e1[64], e2[64], rr[4], of[2];
    const int tid   = threadIdx.x;
    const int cls   = blockIdx.x >> 4;
    const int chunk = blockIdx.x & 15;
    const float chv = (cls & 2) ? 0.25f : -0.25f;
    const float cwv = (cls & 1) ? 0.25f : -0.25f;

    if (tid < 64) {
        float h = bw1[tid*3+0]*0.5f + bw1[tid*3+1]*chv + bw1[tid*3+2]*cwv + bb1[tid];
        e1[tid] = fmaxf(h, 0.f);
    }
    __syncthreads();
    if (tid < 64) {
        float s = bb2[tid];
        for (int i = 0; i < 64; ++i) s += bw2[tid*64+i]*e1[i];
        e2[tid] = fmaxf(s, 0.f);
    }
    __syncthreads();
    if (tid < 6) {
        if (tid < 4) {
            float s = rb[tid];
            for (int i = 0; i < 64; ++i) s += rw[tid*64+i]*e2[i];
            rr[tid] = 1.f/(1.f+expf(-s));
        } else {
            const int d = tid - 4;
            float s = ob[d];
            for (int i = 0; i < 64; ++i) s += ow[d*64+i]*e2[i];
            of[d] = s;
        }
    }
    __syncthreads();
    const float r0 = rr[0], r1 = rr[1], r2 = rr[2], r3 = rr[3];

    if (tid < 128) {
        const int idx = chunk*128 + tid;
        const int o = idx >> 7, c = idx & 127;
        const float v = r0*wcomp[idx] + r1*wcomp[2048+idx]
                      + r2*wcomp[4096+idx] + r3*wcomp[6144+idx];
        ws[WC_OFF + cls*2048 + c*16 + o] = v;     // transposed [c][o]
    } else {
        const int idx = chunk*128 + (tid - 128);
        ws[WE_OFF + cls*2048 + idx] =             // native [c][o]
            r0*wexp[idx] + r1*wexp[2048+idx] + r2*wexp[4096+idx] + r3*wexp[6144+idx];
    }
    if (chunk == 0 && tid == 0) {
        const float fx = cwv + of[0];
        const float fy = chv + of[1];
        const float Dx = floorf(fx), Dy = floorf(fy);
        ws[TAP_OFF + cls*4 + 0] = fx - Dx;
        ws[TAP_OFF + cls*4 + 1] = fy - Dy;
        ws[TAP_OFF + cls*4 + 2] = Dx;
        ws[TAP_OFF + cls*4 + 3] = Dy;
    }
}

// ---------------------------------------------------------------------------
// K1b: fold M[cls] = We_mix * Wc_mix + I, store bf16 row-major [c_out][c_in].
// 64 blocks x 256 threads; each thread = 4 consecutive c_in of one c_out.
__global__ __launch_bounds__(256) void k1b_fold(
    const float* __restrict__ wsr, unsigned short* __restrict__ Mw)
{
    const int t   = blockIdx.x*256 + threadIdx.x;    // 0..16383
    const int cls = t >> 12;
    const int rem = t & 4095;
    const int co  = rem >> 5;            // c_out 0..127
    const int ci0 = (rem & 31) * 4;      // c_in base
    const float* we = wsr + WE_OFF + cls*2048 + co*16;

    float m[4];
    #pragma unroll
    for (int q = 0; q < 4; ++q) {
        const float* wc = wsr + WC_OFF + cls*2048 + (ci0+q)*16;
        float s = 0.f;
        #pragma unroll
        for (int o = 0; o < 16; ++o) s += we[o]*wc[o];
        if (co == ci0 + q) s += 1.f;     // residual identity folded in
        m[q] = s;
    }
    uint2 v;
    v.x = f2bf(m[0]) | (f2bf(m[1]) << 16);
    v.y = f2bf(m[2]) | (f2bf(m[3]) << 16);
    *reinterpret_cast<uint2*>(Mw + (size_t)cls*16384 + co*128 + ci0) = v;
}

// Edge remap (verified rounds 1-6).
__device__ __forceinline__ void remap_axis(int c0, int last, float w0, float w1,
                                           int& base, float& a0, float& a1)
{
    base = min(max(c0, 0), last - 1);
    if (c0 >= 0 && c0 < last) { a0 = w0;  a1 = w1;  }
    else if (c0 == -1)        { a0 = w1;  a1 = 0.f; }
    else if (c0 == last)      { a0 = 0.f; a1 = w0;  }
    else                      { a0 = 0.f; a1 = 0.f; }
}

// ---------------------------------------------------------------------------
// K2: fused gather + (M+I)@fea via MFMA. 2304 blocks x 256 threads (4 waves).
// Block = 64 consecutive half-res pixels of ONE class (round-4 tiling/swizzle,
// proven FETCH~10MB / exact WRITE). Producer: thread (px=xl, grp) computes fea
// for 32 channels, bf16-packs into swizzled LDS [px][ch]. GEMM: wave grp owns
// out-channels [32g,32g+32): A = M rows (global, L2-hot, 16B/lane), B = fea
// (ds_read_b128), 32 x mfma_f32_16x16x32_bf16, D stored direct (residual in M).
__global__ __launch_bounds__(256) void k2_mfma(
    const float* __restrict__ x, const float* __restrict__ wsr,
    const unsigned short* __restrict__ Mw, float* __restrict__ out)
{
    __shared__ __align__(16) unsigned short lF[64*128];   // 16 KB, swizzled

    const int tid = threadIdx.x;
    const int xl  = tid & 63;       // lane in wave = pixel slot (producer)
    const int grp = tid >> 6;

    // XCD-paired swizzle (round 4): 2304 = 8 XCDs * 288; 4 classes of a tile
    // are consecutive on one XCD.
    const int n = blockIdx.x;
    const int w = (n & 7) * 288 + (n >> 3);
    const int px_ = w & 1, py = (w >> 1) & 1;
    const int w2 = w >> 2;
    const int tile = w2 % 144;
    const int b    = w2 / 144;
    const int cls  = (py << 1) | px_;

    // ---- taps for this thread's pixel ----
    const int pix = tile*64 + xl;
    const int j = pix / 96;
    const int i = pix - j*96;

    const float tx = wsr[TAP_OFF + cls*4 + 0];
    const float ty = wsr[TAP_OFF + cls*4 + 1];
    const int   Dx = (int)wsr[TAP_OFF + cls*4 + 2];
    const int   Dy = (int)wsr[TAP_OFF + cls*4 + 3];
    int cb, rbw; float ax0, ax1, ay0, ay1;
    remap_axis(i + Dx, Ww - 1, 1.f - tx, tx, cb,  ax0, ax1);
    remap_axis(j + Dy, Hh - 1, 1.f - ty, ty, rbw, ay0, ay1);
    const float w00 = ay0*ax0, w01 = ay0*ax1, w10 = ay1*ax0, w11 = ay1*ax1;
    const float* xb = x + (size_t)b*Cc*HW + rbw*Ww + cb;

    // ---- producer: fea (fp32) -> bf16 pairs -> swizzled LDS [px][ch] ----
    // byte addr = px*256 + ch*2, XOR ((px&7)<<4)
    #pragma unroll
    for (int q = 0; q < 8; ++q) {
        const int c = grp*32 + q*4;
        const float* p0 = xb + (size_t)(c  )*HW;
        const float* p1 = xb + (size_t)(c+1)*HW;
        const float* p2 = xb + (size_t)(c+2)*HW;
        const float* p3 = xb + (size_t)(c+3)*HW;
        const float f0 = w00*p0[0] + w01*p0[1] + w10*p0[Ww] + w11*p0[Ww+1];
        const float f1 = w00*p1[0] + w01*p1[1] + w10*p1[Ww] + w11*p1[Ww+1];
        const float f2 = w00*p2[0] + w01*p2[1] + w10*p2[Ww] + w11*p2[Ww+1];
        const float f3 = w00*p3[0] + w01*p3[1] + w10*p3[Ww] + w11*p3[Ww+1];
        uint2 v;
        v.x = f2bf(f0) | (f2bf(f1) << 16);
        v.y = f2bf(f2) | (f2bf(f3) << 16);
        int byte = xl*256 + c*2;
        byte ^= (xl & 7) << 4;
        *reinterpret_cast<uint2*>(reinterpret_cast<char*>(lF) + byte) = v;
    }

    // ---- A fragments: M rows for this wave's 32 out-channels (L2-hot) ----
    // lane l: row = 32g+16t+(l&15), k = 32kk + (l>>4)*8 .. +8  (16B load)
    const unsigned short* Mc = Mw + (size_t)cls*16384;
    s16x8 a[2][4];
    #pragma unroll
    for (int t = 0; t < 2; ++t)
        #pragma unroll
        for (int kk = 0; kk < 4; ++kk) {
            const int row = 32*grp + 16*t + (xl & 15);
            const unsigned short* ap = Mc + row*128 + kk*32 + ((xl >> 4) & 3)*8;
            a[t][kk] = *reinterpret_cast<const s16x8*>(ap);
        }

    __syncthreads();

    // ---- GEMM: D[128 x 64px] = M @ fea ----
    f32x4 acc[2][4];
    #pragma unroll
    for (int t = 0; t < 2; ++t)
        #pragma unroll
        for (int nn = 0; nn < 4; ++nn) acc[t][nn] = (f32x4){0.f, 0.f, 0.f, 0.f};

    #pragma unroll
    for (int kk = 0; kk < 4; ++kk) {
        #pragma unroll
        for (int nn = 0; nn < 4; ++nn) {
            // B frag lane l: px = 16nn+(l&15), ch = 32kk+(l>>4)*8 (8 contig bf16)
            int byte = (nn*16 + (xl & 15))*256 + kk*64 + ((xl >> 4) & 3)*16;
            byte ^= (xl & 7) << 4;
            const s16x8 bf = *reinterpret_cast<const s16x8*>(
                reinterpret_cast<const char*>(lF) + byte);
            acc[0][nn] = __builtin_amdgcn_mfma_f32_16x16x32_bf16(a[0][kk], bf, acc[0][nn], 0, 0, 0);
            acc[1][nn] = __builtin_amdgcn_mfma_f32_16x16x32_bf16(a[1][kk], bf, acc[1][nn], 0, 0, 0);
        }
    }

    // ---- store: D lane l reg r -> ch = 32g+16t+(l>>4)*4+r, px = 16nn+(l&15) ----
    #pragma unroll
    for (int t = 0; t < 2; ++t)
        #pragma unroll
        for (int nn = 0; nn < 4; ++nn) {
            const int pix2 = tile*64 + nn*16 + (xl & 15);
            const int j2 = pix2 / 96;
            const int i2 = pix2 - j2*96;
            const int yg = 2*j2 + py;
            const int xg = 2*i2 + px_;
            const int ch0 = 32*grp + 16*t + ((xl >> 4) & 3)*4;
            float* op = out + ((size_t)(b*Cc + ch0)*H2c + yg)*W2c + xg;
            #pragma unroll
            for (int r = 0; r < 4; ++r)
                op[(size_t)r*(H2c*W2c)] = acc[t][nn][r];
        }
}

extern "C" void kernel_launch(void* const* d_in, const int* in_sizes, int n_in,
                              void* d_out, int out_size, void* d_ws, size_t ws_size,
                              hipStream_t stream) {
    const float* x     = (const float*)d_in[0];
    const float* wcomp = (const float*)d_in[1];
    const float* wexp  = (const float*)d_in[2];
    const float* bw1   = (const float*)d_in[3];
    const float* bb1   = (const float*)d_in[4];
    const float* bw2   = (const float*)d_in[5];
    const float* bb2   = (const float*)d_in[6];
    const float* rw    = (const float*)d_in[7];
    const float* rb    = (const float*)d_in[8];
    const float* ow    = (const float*)d_in[9];
    const float* ob    = (const float*)d_in[10];
    float* out = (float*)d_out;
    float* ws  = (float*)d_ws;
    unsigned short* Mw = (unsigned short*)(ws + M_OFF);   // ~194 KB total used

    k1_mix<<<64, 256, 0, stream>>>(wcomp, wexp, bw1, bb1, bw2, bb2, rw, rb, ow, ob, ws);
    k1b_fold<<<64, 256, 0, stream>>>(ws, Mw);
    k2_mfma<<<2304, 256, 0, stream>>>(x, ws, Mw, out);
}